// Round 1
// baseline (4611.615 us; speedup 1.0000x reference)
//
#include <hip/hip_runtime.h>
#include <hip/hip_bf16.h>

// SelfAttention (SAGAN-style): B=8, C=256, N=64*64=4096, Cp=32, fp32.
// Structure:
//   kernel 1 (qkv): x (B,C,N) -> qbuf (B,N,32), kbuf (B,N,32) [=k^T], vbuf (B,N,256) [=v^T]
//   kernel 2 (attn): flash-style online softmax over m, O = attn @ V^T, out = gamma*o + x
// Workspace: (1M + 1M + 8M) floats = 40 MB.

constexpr int C  = 256;
constexpr int CP = 32;
constexpr int NPOS = 4096;
constexpr int NB = 8;

// ---------------------------------------------------------------------------
// QKV projection. Grid: NB * (NPOS/64) blocks, 256 threads.
// Each block: stage x[:, n0:n0+64] (64 KB LDS). Wave g owns positions
// [n0+16g, n0+16g+16); lane = output row. LDS reads are wave-uniform
// broadcasts (conflict-free); global stores have consecutive rows across
// lanes -> coalesced.
// ---------------------------------------------------------------------------
__global__ __launch_bounds__(256) void qkv_kernel(
    const float* __restrict__ x,
    const float* __restrict__ Wq, const float* __restrict__ bq,
    const float* __restrict__ Wk, const float* __restrict__ bk,
    const float* __restrict__ Wv, const float* __restrict__ bv,
    float* __restrict__ qbuf, float* __restrict__ kbuf, float* __restrict__ vbuf)
{
    __shared__ float xl[C][64];    // 64 KB
    const int tid = threadIdx.x;
    const int b  = blockIdx.x >> 6;          // 64 tiles per batch
    const int n0 = (blockIdx.x & 63) << 6;

    // Stage x tile: coalesced float4 loads along n.
    const float* xb = x + (size_t)b * C * NPOS + n0;
    for (int idx4 = tid; idx4 < C * 16; idx4 += 256) {
        int c = idx4 >> 4, j4 = idx4 & 15;
        float4 gg = *reinterpret_cast<const float4*>(xb + (size_t)c * NPOS + j4 * 4);
        *reinterpret_cast<float4*>(&xl[c][j4 * 4]) = gg;
    }
    __syncthreads();

    const int lane = tid & 63, g = tid >> 6;

    for (int grp = 0; grp < 5; ++grp) {
        const float* Wmat; const float* bias; float* ob; int r; int dd;
        if (grp == 0) {
            if (lane < 32) { Wmat = Wq; bias = bq; ob = qbuf; r = lane; }
            else           { Wmat = Wk; bias = bk; ob = kbuf; r = lane - 32; }
            dd = CP;
        } else {
            Wmat = Wv; bias = bv; ob = vbuf; r = (grp - 1) * 64 + lane; dd = C;
        }
        float acc[16];
        const float bval = bias[r];
        #pragma unroll
        for (int jj = 0; jj < 16; ++jj) acc[jj] = bval;

        const float* wrow = Wmat + (size_t)r * C;
        for (int c = 0; c < C; ++c) {
            float w = wrow[c];                 // per-lane row stream, L1-resident
            const float4* xv = reinterpret_cast<const float4*>(&xl[c][g * 16]);
            #pragma unroll
            for (int j4 = 0; j4 < 4; ++j4) {   // wave-uniform LDS broadcast
                float4 xq = xv[j4];
                acc[j4*4+0] = fmaf(w, xq.x, acc[j4*4+0]);
                acc[j4*4+1] = fmaf(w, xq.y, acc[j4*4+1]);
                acc[j4*4+2] = fmaf(w, xq.z, acc[j4*4+2]);
                acc[j4*4+3] = fmaf(w, xq.w, acc[j4*4+3]);
            }
        }
        const size_t base = (size_t)b * NPOS + n0 + g * 16;
        #pragma unroll
        for (int jj = 0; jj < 16; ++jj)
            ob[(base + jj) * dd + r] = acc[jj];   // lanes: consecutive r -> coalesced
    }
}

// ---------------------------------------------------------------------------
// Flash attention. Grid: NB * (NPOS/64) blocks, 256 threads (4 waves).
// XCD swizzle: b = blockIdx & 7 so each XCD's L2 caches one batch's K/V.
// Lane owns query position n = qt*64 + (tid&63); wave g owns V-channel group
// [64g, 64g+64). Scores computed once per tile (waves split the 32 m-rows),
// shared via LDS; online softmax state kept per-thread (redundant x4, cheap).
// ---------------------------------------------------------------------------
__global__ __launch_bounds__(256) void attn_kernel(
    const float* __restrict__ qbuf, const float* __restrict__ kbuf,
    const float* __restrict__ vbuf, const float* __restrict__ x,
    const float* __restrict__ gamma_p, float* __restrict__ out)
{
    __shared__ float sc[32][64];   // scores tile: [m_local][n_local], 8 KB
    const int tid = threadIdx.x;
    const int b  = blockIdx.x & 7;        // XCD-aware swizzle
    const int qt = blockIdx.x >> 3;
    const int nl = tid & 63, g = tid >> 6;
    const int n = qt * 64 + nl;

    float4 q[8];
    const float4* qp = reinterpret_cast<const float4*>(qbuf + ((size_t)b * NPOS + n) * CP);
    #pragma unroll
    for (int i = 0; i < 8; ++i) q[i] = qp[i];

    float acc[64];
    #pragma unroll
    for (int i = 0; i < 64; ++i) acc[i] = 0.f;
    float mx = -1e30f, l = 0.f;

    for (int mt = 0; mt < NPOS / 32; ++mt) {
        // phase 1: this wave computes 8 of the 32 scores rows (no redundancy)
        #pragma unroll
        for (int ii = 0; ii < 8; ++ii) {
            const int mrow = mt * 32 + g * 8 + ii;
            const float4* kp = reinterpret_cast<const float4*>(
                kbuf + ((size_t)b * NPOS + mrow) * CP);   // wave-uniform
            float s = 0.f;
            #pragma unroll
            for (int i = 0; i < 8; ++i) {
                float4 kv = kp[i];
                s = fmaf(q[i].x, kv.x, s); s = fmaf(q[i].y, kv.y, s);
                s = fmaf(q[i].z, kv.z, s); s = fmaf(q[i].w, kv.w, s);
            }
            sc[g * 8 + ii][nl] = s;   // consecutive nl -> conflict-free
        }
        __syncthreads();

        // phase 2: online softmax + PV accumulate (64 channels per thread)
        float tm = -1e30f;
        #pragma unroll
        for (int i = 0; i < 32; ++i) tm = fmaxf(tm, sc[i][nl]);
        const float nm = fmaxf(mx, tm);
        const float scale = __expf(mx - nm);
        mx = nm;
        l *= scale;
        #pragma unroll
        for (int i = 0; i < 64; ++i) acc[i] *= scale;

        const float* vb = vbuf + ((size_t)b * NPOS + mt * 32) * C + g * 64;
        for (int i = 0; i < 32; ++i) {
            const float p = __expf(sc[i][nl] - nm);
            l += p;
            const float4* vp = reinterpret_cast<const float4*>(vb + (size_t)i * C); // uniform
            #pragma unroll
            for (int c4 = 0; c4 < 16; ++c4) {
                float4 v = vp[c4];
                acc[c4*4+0] = fmaf(p, v.x, acc[c4*4+0]);
                acc[c4*4+1] = fmaf(p, v.y, acc[c4*4+1]);
                acc[c4*4+2] = fmaf(p, v.z, acc[c4*4+2]);
                acc[c4*4+3] = fmaf(p, v.w, acc[c4*4+3]);
            }
        }
        __syncthreads();   // before next tile overwrites sc
    }

    // epilogue: out = gamma * (acc/l) + x ; lanes n consecutive -> coalesced
    const float inv = 1.0f / l;
    const float gamma = *gamma_p;
    const float* xb = x + (size_t)b * C * NPOS;
    float* ob = out + (size_t)b * C * NPOS;
    for (int jj = 0; jj < 64; ++jj) {
        const int c = g * 64 + jj;
        const size_t idx = (size_t)c * NPOS + n;
        ob[idx] = gamma * (acc[jj] * inv) + xb[idx];
    }
}

extern "C" void kernel_launch(void* const* d_in, const int* in_sizes, int n_in,
                              void* d_out, int out_size, void* d_ws, size_t ws_size,
                              hipStream_t stream) {
    const float* x  = (const float*)d_in[0];
    const float* Wq = (const float*)d_in[1];
    const float* bq = (const float*)d_in[2];
    const float* Wk = (const float*)d_in[3];
    const float* bk = (const float*)d_in[4];
    const float* Wv = (const float*)d_in[5];
    const float* bv = (const float*)d_in[6];
    const float* gamma = (const float*)d_in[7];
    float* out = (float*)d_out;

    // workspace layout: q (1M floats) | k^T (1M) | v^T (8M)  = 40 MB
    float* qbuf = (float*)d_ws;
    float* kbuf = qbuf + (size_t)NB * NPOS * CP;
    float* vbuf = kbuf + (size_t)NB * NPOS * CP;

    qkv_kernel<<<NB * (NPOS / 64), 256, 0, stream>>>(x, Wq, bq, Wk, bk, Wv, bv,
                                                     qbuf, kbuf, vbuf);
    attn_kernel<<<NB * (NPOS / 64), 256, 0, stream>>>(qbuf, kbuf, vbuf, x, gamma, out);
}